// Round 1
// baseline (919.837 us; speedup 1.0000x reference)
//
#include <hip/hip_runtime.h>
#include <math.h>

#define NOFF 44
#define HCONST 16
#define NCONST 4096
#define HDCONST 64

// wave = 4 queries x 16 lanes; lane owns a float4 hd-chunk.
// block = 256 threads = 4 waves = 16 queries. grid = B*H*N/16 = 16384.
__global__ __launch_bounds__(256, 4)
void dsq_attn_kernel(const float* __restrict__ q,
                     const float* __restrict__ k,
                     const float* __restrict__ v,
                     const float* __restrict__ pb,   // [44][16]
                     float* __restrict__ out)
{
    constexpr int OFF[NOFF] = {
        0,1,2,3,4,5,6,7,8,9,10,11,12,13,14,15,16,17,18,19,20,21,22,23,
        24,25,26,27,28,29,30,31,32,
        48,64,96,128,192,256,384,512,768,1024,1536};

    // XCD-aware bijective swizzle: nwg=16384, 8 XCDs -> XCD x gets a
    // contiguous range of 2048 logical blocks (same bh, contiguous n).
    int b    = blockIdx.x;
    int bid0 = (b & 7) * 2048 + (b >> 3);
    int bh    = bid0 >> 8;          // [0,64)  = b*H + h
    int ntile = bid0 & 255;         // [0,256) -> 16 queries each

    int lane = threadIdx.x & 63;
    int wv   = threadIdx.x >> 6;    // wave in block, 0..3
    int qloc = lane >> 4;           // query within wave, 0..3
    int c4   = (lane & 15) << 2;    // hd chunk start, 0,4,...,60

    int n = ntile * 16 + wv * 4 + qloc;
    int h = bh & (HCONST - 1);

    const size_t basebh = (size_t)bh * NCONST * HDCONST;
    const float* qp = q + basebh;
    const float* kp = k + basebh;
    const float* vp = v + basebh;

    const float4 qv = *(const float4*)(qp + (size_t)n * HDCONST + c4);
    const float sc = 0.125f;  // 1/sqrt(64)

    float s[NOFF];
#pragma unroll
    for (int i = 0; i < NOFF; ++i) {
        int d = OFF[i];
        int r = n - d;
        int rc = r < 0 ? 0 : r;
        float4 kv = *(const float4*)(kp + (size_t)rc * HDCONST + c4);
        float t = qv.x * kv.x + qv.y * kv.y + qv.z * kv.z + qv.w * kv.w;
        // allreduce over the 16-lane query group
        t += __shfl_xor(t, 1);
        t += __shfl_xor(t, 2);
        t += __shfl_xor(t, 4);
        t += __shfl_xor(t, 8);
        s[i] = (r >= 0) ? fmaf(t, sc, pb[i * HCONST + h]) : -INFINITY;
    }

    // softmax over 44 (lane-redundant within each query group; d=0 always valid)
    float m = s[0];
#pragma unroll
    for (int i = 1; i < NOFF; ++i) m = fmaxf(m, s[i]);
    float l = 0.0f;
#pragma unroll
    for (int i = 0; i < NOFF; ++i) {
        float e = __expf(s[i] - m);   // exp(-inf)=0 for invalid offsets
        s[i] = e;
        l += e;
    }

    // PV with unnormalized weights; single divide at the end
    float4 acc = make_float4(0.f, 0.f, 0.f, 0.f);
#pragma unroll
    for (int i = 0; i < NOFF; ++i) {
        int d = OFF[i];
        int r = n - d;
        int rc = r < 0 ? 0 : r;
        float4 vv = *(const float4*)(vp + (size_t)rc * HDCONST + c4);
        float e = s[i];               // 0 for invalid -> clamped row harmless
        acc.x = fmaf(e, vv.x, acc.x);
        acc.y = fmaf(e, vv.y, acc.y);
        acc.z = fmaf(e, vv.z, acc.z);
        acc.w = fmaf(e, vv.w, acc.w);
    }

    float inv = 1.0f / l;
    float4 o = make_float4(acc.x * inv, acc.y * inv, acc.z * inv, acc.w * inv);
    *(float4*)(out + basebh + (size_t)n * HDCONST + c4) = o;
}

extern "C" void kernel_launch(void* const* d_in, const int* in_sizes, int n_in,
                              void* d_out, int out_size, void* d_ws, size_t ws_size,
                              hipStream_t stream) {
    const float* q  = (const float*)d_in[0];
    const float* k  = (const float*)d_in[1];
    const float* v  = (const float*)d_in[2];
    const float* pb = (const float*)d_in[3];
    float* out = (float*)d_out;

    // B*H*N / 16 queries-per-block = 4*16*4096/16 = 16384 blocks
    dim3 grid(16384), block(256);
    hipLaunchKernelGGL(dsq_attn_kernel, grid, block, 0, stream, q, k, v, pb, out);
}

// Round 8
// 300.891 us; speedup vs baseline: 3.0570x; 3.0570x over previous
//
#include <hip/hip_runtime.h>
#include <math.h>

#define NOFF 44
#define NSP 11
#define HCONST 16
#define NCONST 4096
#define HD 64
#define QB 16          // queries per block
#define DROWS 48       // QB + 32 dense-band rows staged in LDS
#define LPAD 68        // 64 floats + 4 pad -> row base rotates 4 banks/row

// 16-lane-group allreduce, pure-VALU DPP (no ds_swizzle).
template <int CTRL>
__device__ __forceinline__ float dpp_add(float x) {
    int yi = __builtin_amdgcn_update_dpp(0, __float_as_int(x), CTRL, 0xf, 0xf, true);
    return x + __int_as_float(yi);
}
__device__ __forceinline__ float group16_allreduce(float t) {
    t = dpp_add<0xB1>(t);   // quad_perm xor1
    t = dpp_add<0x4E>(t);   // quad_perm xor2  -> quad sums
    t = dpp_add<0x141>(t);  // row_half_mirror -> quad-pair sums
    t = dpp_add<0x140>(t);  // row_mirror      -> full 16-lane sum
    return t;
}

// wave = 4 queries x 16 lanes; lane owns a float4 hd-chunk.
// block = 256 threads = 16 queries; dense k/v band staged in LDS.
__global__ __launch_bounds__(256, 4)
void dsq_attn_kernel(const float* __restrict__ q,
                     const float* __restrict__ k,
                     const float* __restrict__ v,
                     const float* __restrict__ pb,   // [44][16]
                     float* __restrict__ out)
{
    constexpr int SOFF[NSP] = {48,64,96,128,192,256,384,512,768,1024,1536};

    __shared__ float k_lds[DROWS * LPAD];
    __shared__ float v_lds[DROWS * LPAD];

    // XCD-aware bijective swizzle (16384 blocks, 8 XCDs): each XCD gets a
    // contiguous bid0 range -> concurrent blocks share a ~2.4MB k/v window.
    int b    = blockIdx.x;
    int bid0 = (b & 7) * 2048 + (b >> 3);
    int bh    = bid0 >> 8;          // [0,64) = b*H + h
    int ntile = bid0 & 255;         // 16 queries each

    int lane = threadIdx.x & 63;
    int wv   = threadIdx.x >> 6;    // wave 0..3
    int qloc = lane >> 4;           // query in wave 0..3
    int c4   = (lane & 15) << 2;    // hd chunk 0,4,...,60

    int n0 = ntile * QB;
    int n  = n0 + wv * 4 + qloc;
    int h  = bh & (HCONST - 1);

    const size_t basebh = (size_t)bh * NCONST * HD;
    const float* kp = k + basebh;
    const float* vp = v + basebh;

    // ---- cooperative stage of dense band rows [n0-32, n0+16) ----
    // 768 float4 per tensor; 256 threads x 3; coalesced.
#pragma unroll
    for (int t0 = 0; t0 < 3; ++t0) {
        int t   = (int)threadIdx.x + t0 * 256;
        int row = t >> 4;
        int c   = (t & 15) << 2;
        int gr  = n0 - 32 + row;
        gr = gr < 0 ? 0 : gr;       // clamped rows are masked later (e=0)
        *(float4*)(k_lds + row * LPAD + c) = *(const float4*)(kp + (size_t)gr * HD + c);
        *(float4*)(v_lds + row * LPAD + c) = *(const float4*)(vp + (size_t)gr * HD + c);
    }

    const float4 qv = *(const float4*)(q + basebh + (size_t)n * HD + c4);
    const float sc = 0.125f;        // 1/sqrt(64)

    // ---- sparse k prefetch (global, 11-deep) ----
    float4 kb[NSP];
#pragma unroll
    for (int j = 0; j < NSP; ++j) {
        int r = n - SOFF[j];
        int rc = r < 0 ? 0 : r;
        kb[j] = *(const float4*)(kp + (size_t)rc * HD + c4);
    }

    __syncthreads();

    float s[NOFF];
    int rbase = wv * 4 + qloc + 32;   // LDS row for offset d is rbase - d

    // ---- dense QK from LDS (offsets 0..32) ----
#pragma unroll
    for (int d = 0; d <= 32; ++d) {
        float4 kv = *(const float4*)(k_lds + (rbase - d) * LPAD + c4);
        float t = qv.x * kv.x + qv.y * kv.y + qv.z * kv.z + qv.w * kv.w;
        t = group16_allreduce(t);
        s[d] = (n - d >= 0) ? fmaf(t, sc, pb[d * HCONST + h]) : -INFINITY;
    }
    // ---- sparse QK from prefetched regs ----
#pragma unroll
    for (int j = 0; j < NSP; ++j) {
        float4 kv = kb[j];
        float t = qv.x * kv.x + qv.y * kv.y + qv.z * kv.z + qv.w * kv.w;
        t = group16_allreduce(t);
        s[33 + j] = (n - SOFF[j] >= 0) ? fmaf(t, sc, pb[(33 + j) * HCONST + h]) : -INFINITY;
    }

    // ---- sparse v prefetch (in flight during softmax VALU) ----
    float4 vb[NSP];
#pragma unroll
    for (int j = 0; j < NSP; ++j) {
        int r = n - SOFF[j];
        int rc = r < 0 ? 0 : r;
        vb[j] = *(const float4*)(vp + (size_t)rc * HD + c4);
    }

    // ---- softmax over 44 (lane-redundant; d=0 always valid) ----
    float m = s[0];
#pragma unroll
    for (int i = 1; i < NOFF; ++i) m = fmaxf(m, s[i]);
    float l = 0.0f;
#pragma unroll
    for (int i = 0; i < NOFF; ++i) {
        float e = __expf(s[i] - m);   // exp(-inf)=0 for invalid offsets
        s[i] = e;
        l += e;
    }

    // ---- PV: dense from LDS, sparse from regs ----
    float4 acc = make_float4(0.f, 0.f, 0.f, 0.f);
#pragma unroll
    for (int d = 0; d <= 32; ++d) {
        float4 vv = *(const float4*)(v_lds + (rbase - d) * LPAD + c4);
        float e = s[d];
        acc.x = fmaf(e, vv.x, acc.x);
        acc.y = fmaf(e, vv.y, acc.y);
        acc.z = fmaf(e, vv.z, acc.z);
        acc.w = fmaf(e, vv.w, acc.w);
    }
#pragma unroll
    for (int j = 0; j < NSP; ++j) {
        float4 vv = vb[j];
        float e = s[33 + j];          // 0 for invalid -> clamped row harmless
        acc.x = fmaf(e, vv.x, acc.x);
        acc.y = fmaf(e, vv.y, acc.y);
        acc.z = fmaf(e, vv.z, acc.z);
        acc.w = fmaf(e, vv.w, acc.w);
    }

    float inv = 1.0f / l;
    float4 o = make_float4(acc.x * inv, acc.y * inv, acc.z * inv, acc.w * inv);
    *(float4*)(out + basebh + (size_t)n * HD + c4) = o;
}

extern "C" void kernel_launch(void* const* d_in, const int* in_sizes, int n_in,
                              void* d_out, int out_size, void* d_ws, size_t ws_size,
                              hipStream_t stream) {
    const float* q  = (const float*)d_in[0];
    const float* k  = (const float*)d_in[1];
    const float* v  = (const float*)d_in[2];
    const float* pb = (const float*)d_in[3];
    float* out = (float*)d_out;

    dim3 grid(16384), block(256);
    hipLaunchKernelGGL(dsq_attn_kernel, grid, block, 0, stream, q, k, v, pb, out);
}